// Round 15
// baseline (163.760 us; speedup 1.0000x reference)
//
#include <hip/hip_runtime.h>
#include <hip/hip_fp16.h>

#define Nn 2048
#define Ff 64
#define Uu 64
#define NT 256
#define NCH 4           // chunks of 512 cols
#define G1S 68

typedef _Float16 f16x4 __attribute__((ext_vector_type(4)));
typedef _Float16 f16x8 __attribute__((ext_vector_type(8)));
typedef float    f32x4 __attribute__((ext_vector_type(4)));

#define MFMA32(a,b,c) __builtin_amdgcn_mfma_f32_16x16x32_f16(a,b,c,0,0,0)

// LDS map: P [2 bufs][2 batches][8KB] = 32KB, zero block, sums, g1
#define OPB  0
#define OZB  32768     // 128B zeros (A-frag rows 8..15)
#define OWS  32896     // 16 floats
#define OINV 32960     // 16 floats
#define OG1  33024     // 2 x 8 x G1S floats = 4352B
#define SMSZ 37376     // <= 40KB -> 4 blocks/CU

// ---- X transpose: Xt[b][f][k] = (f16) X[b][k][f] (validated R4-R14) ----
__global__ __launch_bounds__(256) void transposeX(const float* __restrict__ X,
                                                  _Float16* __restrict__ Xt) {
    __shared__ _Float16 tile[64][65];
    const int b = blockIdx.x, kt = blockIdx.y;
    #pragma unroll
    for (int i = 0; i < 16; ++i) {
        int e  = i * 256 + threadIdx.x;
        int kk = e >> 6, ff = e & 63;
        tile[ff][kk] = (_Float16)X[((size_t)b * Nn + kt * 64 + kk) * Ff + ff];
    }
    __syncthreads();
    #pragma unroll
    for (int i = 0; i < 16; ++i) {
        int e  = i * 256 + threadIdx.x;
        int ff = e >> 6, kk = e & 63;
        Xt[((size_t)b * Ff + ff) * Nn + kt * 64 + kk] = tile[ff][kk];
    }
}

// A-unit: batch0 D/W + shared G/K (6x 1KB contiguous loads — R6-proven)
#define ISSUEA(C, UR, H) {                                          \
    const size_t _o = (size_t)(UR) * Nn + ((size_t)(C) << 9)        \
                    + ((H) << 8) + (lane << 2);                     \
    Ad  = *(const float4*)(dR0 + _o);                               \
    Aw0 = *(const float4*)(wR0 + 3 * _o);                           \
    Aw1 = *(const float4*)(wR0 + 3 * _o + 4);                       \
    Aw2 = *(const float4*)(wR0 + 3 * _o + 8);                       \
    Ag  = *(const float4*)(gR + _o);                                \
    Ak  = *(const float4*)(kR + _o);                                \
}
// B-unit: batch1 D/W only (4 loads) — G/K comes from the carry regs
#define ISSUEB(C, UR, H) {                                          \
    const size_t _o = (size_t)(UR) * Nn + ((size_t)(C) << 9)        \
                    + ((H) << 8) + (lane << 2);                     \
    Bd  = *(const float4*)(dR1 + _o);                               \
    Bw0 = *(const float4*)(wR1 + 3 * _o);                           \
    Bw1 = *(const float4*)(wR1 + 3 * _o + 4);                       \
    Bw2 = *(const float4*)(wR1 + 3 * _o + 8);                       \
}

#define CONSUMEA(P0B, UR, H) {                                                  \
    const int _tr = row0 + (UR);                                                \
    float e0 = __expf(fminf(Ad.x*Aw0.x + Ag.x*Aw0.y + Ak.x*Aw0.z, 11.f));       \
    float e1 = __expf(fminf(Ad.y*Aw0.w + Ag.y*Aw1.x + Ak.y*Aw1.y, 11.f));       \
    float e2 = __expf(fminf(Ad.z*Aw1.z + Ag.z*Aw1.w + Ak.z*Aw2.x, 11.f));       \
    float e3 = __expf(fminf(Ad.w*Aw2.y + Ag.w*Aw2.z + Ak.w*Aw2.w, 11.f));       \
    f16x4 h = {(_Float16)e0, (_Float16)e1, (_Float16)e2, (_Float16)e3};         \
    rs0[UR] += (float)h[0] + (float)h[1] + (float)h[2] + (float)h[3];           \
    const int _ba = (_tr * 1024 + ((H) << 9) + (lane << 3)) ^ ((_tr & 7) << 4); \
    *(f16x4*)((P0B) + _ba) = h;                                                 \
    gC = Ag; kC = Ak;   /* carry G/K for batch1 (A-slot reissued next) */       \
}
#define CONSUMEB(P1B, UR, H) {                                                  \
    const int _tr = row0 + (UR);                                                \
    float e0 = __expf(fminf(Bd.x*Bw0.x + gC.x*Bw0.y + kC.x*Bw0.z, 11.f));       \
    float e1 = __expf(fminf(Bd.y*Bw0.w + gC.y*Bw1.x + kC.y*Bw1.y, 11.f));       \
    float e2 = __expf(fminf(Bd.z*Bw1.z + gC.z*Bw1.w + kC.z*Bw2.x, 11.f));       \
    float e3 = __expf(fminf(Bd.w*Bw2.y + gC.w*Bw2.z + kC.w*Bw2.w, 11.f));       \
    f16x4 h = {(_Float16)e0, (_Float16)e1, (_Float16)e2, (_Float16)e3};         \
    rs1[UR] += (float)h[0] + (float)h[1] + (float)h[2] + (float)h[3];           \
    const int _ba = (_tr * 1024 + ((H) << 9) + (lane << 3)) ^ ((_tr & 7) << 4); \
    *(f16x4*)((P1B) + _ba) = h;                                                 \
}

// depth-2 interleaved stage of one 512-col chunk (2 rows x 2 halves x 2 batches)
#define STAGE_CHUNK(P0B, P1B, C) {        \
    ISSUEA(C, 0, 0);                      \
    ISSUEB(C, 0, 0);                      \
    CONSUMEA(P0B, 0, 0);                  \
    ISSUEA(C, 0, 1);                      \
    CONSUMEB(P1B, 0, 0);                  \
    ISSUEB(C, 0, 1);                      \
    CONSUMEA(P0B, 0, 1);                  \
    ISSUEA(C, 1, 0);                      \
    CONSUMEB(P1B, 0, 1);                  \
    ISSUEB(C, 1, 0);                      \
    CONSUMEA(P0B, 1, 0);                  \
    ISSUEA(C, 1, 1);                      \
    CONSUMEB(P1B, 1, 0);                  \
    ISSUEB(C, 1, 1);                      \
    CONSUMEA(P0B, 1, 1);                  \
    CONSUMEB(P1B, 1, 1);                  \
}

// 16 MFMA steps over one staged 512-col chunk for one 16-col tile.
// A-frag lanes r>=8 read the zeroed block (C rows 8..15 discarded).
#define MFMA_TILE(PBUF, XC, ACC) {                                            \
    f16x8 p0 = *(const f16x8*)((XC));                                         \
    f16x8 p1 = *(const f16x8*)((XC) + 32);                                    \
    f16x8 p2 = *(const f16x8*)((XC) + 64);                                    \
    f16x8 p3 = *(const f16x8*)((XC) + 96);                                    \
    f16x8 p4 = *(const f16x8*)((XC) + 128);                                   \
    f16x8 p5 = *(const f16x8*)((XC) + 160);                                   \
    f16x8 p6 = *(const f16x8*)((XC) + 192);                                   \
    f16x8 p7 = *(const f16x8*)((XC) + 224);                                   \
    _Pragma("unroll")                                                         \
    for (int kk = 0; kk < 8; ++kk) {                                          \
        const int aa = (r * 1024 + kk * 64 + kg * 16) ^ ((r & 7) << 4);       \
        const char* ap = (r < 8) ? ((PBUF) + aa) : zp;                        \
        f16x8 af = *(const f16x8*)ap;                                         \
        f16x8 bv = (kk==0)?p0:(kk==1)?p1:(kk==2)?p2:(kk==3)?p3:               \
                   (kk==4)?p4:(kk==5)?p5:(kk==6)?p6:p7;                       \
        ACC = MFMA32(af, bv, ACC);                                            \
    }                                                                         \
    p0 = *(const f16x8*)((XC) + 256);                                         \
    p1 = *(const f16x8*)((XC) + 288);                                         \
    p2 = *(const f16x8*)((XC) + 320);                                         \
    p3 = *(const f16x8*)((XC) + 352);                                         \
    p4 = *(const f16x8*)((XC) + 384);                                         \
    p5 = *(const f16x8*)((XC) + 416);                                         \
    p6 = *(const f16x8*)((XC) + 448);                                         \
    p7 = *(const f16x8*)((XC) + 480);                                         \
    _Pragma("unroll")                                                         \
    for (int kk = 0; kk < 8; ++kk) {                                          \
        const int aa = (r * 1024 + (kk + 8) * 64 + kg * 16) ^ ((r & 7) << 4); \
        const char* ap = (r < 8) ? ((PBUF) + aa) : zp;                        \
        f16x8 af = *(const f16x8*)ap;                                         \
        f16x8 bv = (kk==0)?p0:(kk==1)?p1:(kk==2)?p2:(kk==3)?p3:               \
                   (kk==4)?p4:(kk==5)?p5:(kk==6)?p6:p7;                       \
        ACC = MFMA32(af, bv, ACC);                                            \
    }                                                                         \
}

// Block = 8 rows x 2 batches, 256 threads, grid 1024 (4 blocks/CU, 16
// streaming waves/CU — the full R6 rate recipe) at the NB=2 byte count
// (683 MB vs 790): Geo/KL loaded once per chunk, shared via carry regs.
__global__ __launch_bounds__(NT, 4) void fused_gcn(
    const _Float16* __restrict__ Xt,  // [B,F,N] f16
    const float* __restrict__ Dyn,    // [B,N,N]
    const float* __restrict__ Wf,     // [B,N,N,3]
    const float* __restrict__ Geo,    // [N,N]
    const float* __restrict__ KLm,    // [N,N]
    const float* __restrict__ Wd,     // [F,U]
    const float* __restrict__ bdv,    // [U]
    float* __restrict__ out)          // [B,N,U]
{
    __shared__ __align__(16) char SM[SMSZ];

    const int t    = threadIdx.x;
    const int lane = t & 63;
    const int wid  = t >> 6;           // 0..3
    const int r    = lane & 15;
    const int kg   = lane >> 4;
    const int rg   = blockIdx.x & 255;
    const int pp   = blockIdx.x >> 8;
    const int n0   = rg << 3;          // 8 rows per block
    const int b0   = pp * 2, b1 = pp * 2 + 1;
    const int row0 = wid << 1;         // staging rows row0, row0+1 (of 8)

    const float* dR0 = Dyn + ((size_t)b0 * Nn + n0 + row0) * Nn;
    const float* dR1 = Dyn + ((size_t)b1 * Nn + n0 + row0) * Nn;
    const float* wR0 = Wf  + ((size_t)b0 * Nn + n0 + row0) * (size_t)Nn * 3;
    const float* wR1 = Wf  + ((size_t)b1 * Nn + n0 + row0) * (size_t)Nn * 3;
    const float* gR  = Geo + (size_t)(n0 + row0) * Nn;
    const float* kR  = KLm + (size_t)(n0 + row0) * Nn;

    // MFMA role: batch bb = wid>>1, col-tiles tA = (wid&1)*2, tA+1
    const int bb = wid >> 1;
    const int tA = (wid & 1) << 1;
    const int bsel = bb ? b1 : b0;
    const _Float16* xwA = Xt + (size_t)bsel * Ff * Nn
                        + (size_t)(tA * 16 + r) * Nn + (kg << 3);
    const _Float16* xwB = xwA + (size_t)16 * Nn;
    const char* zp = SM + OZB + kg * 16;

    f32x4 accA = {0.f,0.f,0.f,0.f}, accB = {0.f,0.f,0.f,0.f};
    float rs0[2] = {0.f,0.f}, rs1[2] = {0.f,0.f};
    float4 Ad, Aw0, Aw1, Aw2, Ag, Ak;
    float4 Bd, Bw0, Bw1, Bw2;
    float4 gC, kC;

    // prologue: zero block for A-frag rows 8..15, stage chunk 0
    if (t < 32) ((int*)(SM + OZB))[t] = 0;
    STAGE_CHUNK(SM + OPB, SM + OPB + 8192, 0);
    __syncthreads();

    #pragma unroll 1
    for (int c = 0; c < NCH; ++c) {
        const char* pb = SM + OPB + (c & 1) * 16384 + bb * 8192;
        MFMA_TILE(pb, xwA + ((size_t)c << 9), accA);
        MFMA_TILE(pb, xwB + ((size_t)c << 9), accB);
        if (c + 1 < NCH) {
            char* bn = SM + OPB + ((c + 1) & 1) * 16384;
            STAGE_CHUNK(bn, bn + 8192, c + 1);
        }
        __syncthreads();
    }

    // ---- row sums -> inv (batch0 rows 0-7, batch1 rows 8-15) ----
    float* ws = (float*)(SM + OWS);
    #pragma unroll
    for (int i = 0; i < 2; ++i) {
        float v = rs0[i];
        v += __shfl_xor(v, 1, 64);  v += __shfl_xor(v, 2, 64);
        v += __shfl_xor(v, 4, 64);  v += __shfl_xor(v, 8, 64);
        v += __shfl_xor(v, 16, 64); v += __shfl_xor(v, 32, 64);
        float u = rs1[i];
        u += __shfl_xor(u, 1, 64);  u += __shfl_xor(u, 2, 64);
        u += __shfl_xor(u, 4, 64);  u += __shfl_xor(u, 8, 64);
        u += __shfl_xor(u, 16, 64); u += __shfl_xor(u, 32, 64);
        if (lane == 0) { ws[row0 + i] = v; ws[8 + row0 + i] = u; }
    }
    __syncthreads();
    float* inv = (float*)(SM + OINV);
    if (t < 16) inv[t] = 1.0f / ws[t];
    __syncthreads();

    // ---- normalized G1 (C layout R6-verified; rows 8..15 discarded) ----
    float* g1a = (float*)(SM + OG1);
    float* g1b = g1a + 8 * G1S;
    float* g1w = bb ? g1b : g1a;
    const float* invb = inv + bb * 8;
    #pragma unroll
    for (int i = 0; i < 4; ++i) {
        const int ro = (kg << 2) + i;
        if (ro < 8) {
            g1w[ro * G1S + tA * 16 + r]        = accA[i] * invb[ro];
            g1w[ro * G1S + (tA + 1) * 16 + r]  = accB[i] * invb[ro];
        }
    }
    __syncthreads();

    // ---- Dense(64) + tanh: wave -> batch bb, rows (wid&1)*4..+3 of 8 ----
    const int rw0 = (wid & 1) << 2;
    const float* gg = (bb ? g1b : g1a) + rw0 * G1S;
    float bias = bdv[lane];
    float o0 = bias, o1 = bias, o2 = bias, o3 = bias;
    #pragma unroll 4
    for (int f = 0; f < Ff; ++f) {
        float wdv = Wd[f * Uu + lane];
        o0 += gg[f] * wdv;           o1 += gg[G1S + f] * wdv;
        o2 += gg[2 * G1S + f] * wdv; o3 += gg[3 * G1S + f] * wdv;
    }
    float oo[4] = {o0, o1, o2, o3};
    #pragma unroll
    for (int i = 0; i < 4; ++i) {
        float x  = fminf(fmaxf(oo[i], -15.f), 15.f);
        float ex = __expf(2.f * x);
        out[((size_t)bsel * Nn + n0 + rw0 + i) * Uu + lane] = (ex - 1.f) / (ex + 1.f);
    }
}

extern "C" void kernel_launch(void* const* d_in, const int* in_sizes, int n_in,
                              void* d_out, int out_size, void* d_ws, size_t ws_size,
                              hipStream_t stream) {
    const float* X   = (const float*)d_in[0];
    const float* Dyn = (const float*)d_in[1];
    const float* Wf  = (const float*)d_in[2];
    const float* Geo = (const float*)d_in[3];
    const float* KLm = (const float*)d_in[4];
    const float* Wd  = (const float*)d_in[5];
    const float* bdv = (const float*)d_in[6];
    float* out = (float*)d_out;

    _Float16* Xt = (_Float16*)d_ws;   // 2 MB scratch
    transposeX<<<dim3(8, Nn / 64), dim3(256), 0, stream>>>(X, Xt);
    fused_gcn<<<dim3(256 * 4), dim3(NT), 0, stream>>>(
        Xt, Dyn, Wf, Geo, KLm, Wd, bdv, out);
}

// Round 16
// 126.710 us; speedup vs baseline: 1.2924x; 1.2924x over previous
//
#include <hip/hip_runtime.h>
#include <hip/hip_fp16.h>

#define Nn 2048
#define Ff 64
#define Uu 64
#define NT 256
#define CW 64            // chunk width (cols)
#define NCH 32           // 2048/64
#define G1S 68

typedef _Float16 f16x4 __attribute__((ext_vector_type(4)));
typedef _Float16 f16x8 __attribute__((ext_vector_type(8)));
typedef float    f32x4 __attribute__((ext_vector_type(4)));

#define MFMA32(a,b,c) __builtin_amdgcn_mfma_f32_16x16x32_f16(a,b,c,0,0,0)

// async global->LDS, 16B/lane, per-lane global addr, linear wave-uniform LDS dest
#define GLD16(gp, lp) __builtin_amdgcn_global_load_lds(                      \
    (const __attribute__((address_space(1))) void*)(gp),                     \
    (__attribute__((address_space(3))) void*)(lp), 16, 0, 0)

// ---- X transpose: Xt[b][f][k] = (f16) X[b][k][f] (validated R4-R15) ----
__global__ __launch_bounds__(256) void transposeX(const float* __restrict__ X,
                                                  _Float16* __restrict__ Xt) {
    __shared__ _Float16 tile[64][65];
    const int b = blockIdx.x, kt = blockIdx.y;
    #pragma unroll
    for (int i = 0; i < 16; ++i) {
        int e  = i * 256 + threadIdx.x;
        int kk = e >> 6, ff = e & 63;
        tile[ff][kk] = (_Float16)X[((size_t)b * Nn + kt * 64 + kk) * Ff + ff];
    }
    __syncthreads();
    #pragma unroll
    for (int i = 0; i < 16; ++i) {
        int e  = i * 256 + threadIdx.x;
        int ff = e >> 6, kk = e & 63;
        Xt[((size_t)b * Ff + ff) * Nn + kt * 64 + kk] = tile[ff][kk];
    }
}

// Issue the 6 async loads for this wave's 4 rows of the next chunk, then
// advance the per-lane pointers. Zero VGPR staging; loads stay in flight
// through the exp-pass + MFMA and drain at the chunk-end s_waitcnt.
#define STAGE_ISSUE(P) {                                       \
    char* _db = (char*)&Db[P][0] + wid * 1024;                 \
    char* _gb = (char*)&Gb[P][0] + wid * 1024;                 \
    char* _kb = (char*)&Kb[P][0] + wid * 1024;                 \
    char* _wb = (char*)&Wb[P][0] + wid * 3072;                 \
    GLD16(dG, _db);                                            \
    GLD16(gG, _gb);                                            \
    GLD16(kG, _kb);                                            \
    GLD16(wG0, _wb);                                           \
    GLD16(wG1, _wb + 1024);                                    \
    GLD16(wG2, _wb + 2048);                                    \
    dG += 256; gG += 256; kG += 256;                           \
    wG0 += 768; wG1 += 768; wG2 += 768;                        \
}

__global__ __launch_bounds__(NT, 2) void fused_gcn(
    const _Float16* __restrict__ Xt,  // [B,F,N] f16
    const float* __restrict__ Dyn,    // [B,N,N]
    const float* __restrict__ Wf,     // [B,N,N,3]
    const float* __restrict__ Geo,    // [N,N]
    const float* __restrict__ KLm,    // [N,N]
    const float* __restrict__ Wd,     // [F,U]
    const float* __restrict__ bdv,    // [U]
    float* __restrict__ out)          // [B,N,U]
{
    __shared__ float   Db[2][16 * 64];    // raw D chunk, 2 x 4 KB
    __shared__ float   Wb[2][16 * 192];   // raw W chunk, 2 x 12 KB
    __shared__ float   Gb[2][16 * 64];
    __shared__ float   Kb[2][16 * 64];
    __shared__ _Float16 Pb[2][16 * 64];   // exp(fusion) f16, swizzled
    __shared__ float   g1[16 * G1S];
    __shared__ float   wsumS[16];
    __shared__ float   invS[16];

    const int t    = threadIdx.x;
    const int lane = t & 63;
    const int wid  = t >> 6;
    const int r    = lane & 15;
    const int kg   = lane >> 4;
    const int b    = blockIdx.x >> 7;
    const int n0   = (blockIdx.x & 127) << 4;

    // ---- per-lane global gather pointers (wave owns rows 4*wid..4*wid+3)
    const int lrow = lane >> 4, lq = lane & 15;
    const char* dG = (const char*)(Dyn + ((size_t)b * Nn + n0 + 4 * wid) * Nn)
                     + (size_t)lrow * (Nn * 4) + lq * 16;
    const char* gG = (const char*)(Geo + (size_t)(n0 + 4 * wid) * Nn)
                     + (size_t)lrow * (Nn * 4) + lq * 16;
    const char* kG = (const char*)(KLm + (size_t)(n0 + 4 * wid) * Nn)
                     + (size_t)lrow * (Nn * 4) + lq * 16;
    const char* wbase = (const char*)(Wf + ((size_t)b * Nn + n0 + 4 * wid) * (size_t)Nn * 3);
    // W: 3 x 1KB loads cover 4 rows x 768B linearly; map linear->((row),(colbyte))
    const int lin0 = lane * 16;
    const int lin1 = 1024 + lane * 16;
    const int lin2 = 2048 + lane * 16;
    const int rw0 = (lin0 >= 768) ? 1 : 0;
    const int rw1 = (lin1 >= 1536) ? 2 : 1;
    const int rw2 = (lin2 >= 2304) ? 3 : 2;
    const char* wG0 = wbase + (size_t)rw0 * (Nn * 12) + (lin0 - rw0 * 768);
    const char* wG1 = wbase + (size_t)rw1 * (Nn * 12) + (lin1 - rw1 * 768);
    const char* wG2 = wbase + (size_t)rw2 * (Nn * 12) + (lin2 - rw2 * 768);

    const _Float16* xw = Xt + (size_t)b * Ff * Nn
                       + (size_t)(wid * 16 + r) * Nn + (kg << 3);

    // exp-pass mapping: thread t -> row t>>4, col-quad t&15
    const int erow = t >> 4, eq = t & 15;

    f32x4 acc = {0.f, 0.f, 0.f, 0.f};
    float rs = 0.f;

    // ---- prologue: stage chunk 0, drain, barrier ----
    STAGE_ISSUE(0);
    asm volatile("s_waitcnt vmcnt(0)" ::: "memory");
    __builtin_amdgcn_s_barrier();

    #pragma unroll 1
    for (int c = 0; c < NCH; ++c) {
        const int pc = c & 1;

        // B-frags for this chunk (oldest vmcnt entries -> MFMA waits never
        // drain the async stage queue)
        f16x8 bf0 = *(const f16x8*)(xw);
        f16x8 bf1 = *(const f16x8*)(xw + 32);
        xw += 64;
        __builtin_amdgcn_sched_barrier(0);

        // fire-and-forget stage of chunk c+1
        if (c + 1 < NCH) STAGE_ISSUE(pc ^ 1);
        __builtin_amdgcn_sched_barrier(0);

        // ---- exp-pass on raw chunk c (LDS only) ----
        {
            const float* dd = &Db[pc][erow * 64 + eq * 4];
            const float* gg = &Gb[pc][erow * 64 + eq * 4];
            const float* kk = &Kb[pc][erow * 64 + eq * 4];
            const float* ww = &Wb[pc][erow * 192 + eq * 12];
            float4 dv = *(const float4*)dd;
            float4 gv = *(const float4*)gg;
            float4 kv = *(const float4*)kk;
            float4 w0 = *(const float4*)ww;
            float4 w1 = *(const float4*)(ww + 4);
            float4 w2 = *(const float4*)(ww + 8);
            float e0 = __expf(fminf(dv.x*w0.x + gv.x*w0.y + kv.x*w0.z, 11.f));
            float e1 = __expf(fminf(dv.y*w0.w + gv.y*w1.x + kv.y*w1.y, 11.f));
            float e2 = __expf(fminf(dv.z*w1.z + gv.z*w1.w + kv.z*w2.x, 11.f));
            float e3 = __expf(fminf(dv.w*w2.y + gv.w*w2.z + kv.w*w2.w, 11.f));
            f16x4 h = {(_Float16)e0, (_Float16)e1, (_Float16)e2, (_Float16)e3};
            rs += (float)h[0] + (float)h[1] + (float)h[2] + (float)h[3];
            *(f16x4*)((char*)&Pb[pc][0]
                      + ((erow * 128 + eq * 8) ^ ((erow & 7) << 4))) = h;
        }

        // P visible to all waves: drain DS only (async loads keep flying)
        asm volatile("s_waitcnt lgkmcnt(0)" ::: "memory");
        __builtin_amdgcn_sched_barrier(0);
        __builtin_amdgcn_s_barrier();

        // ---- MFMA: A from swizzled P, B from L2-resident Xt ----
        {
            const char* pbuf = (const char*)&Pb[pc][0];
            f16x8 af0 = *(const f16x8*)(pbuf + ((r * 128 + kg * 16) ^ ((r & 7) << 4)));
            f16x8 af1 = *(const f16x8*)(pbuf + ((r * 128 + 64 + kg * 16) ^ ((r & 7) << 4)));
            acc = MFMA32(af0, bf0, acc);
            acc = MFMA32(af1, bf1, acc);
        }

        // chunk c+1 landed; make it visible
        asm volatile("s_waitcnt vmcnt(0)" ::: "memory");
        __builtin_amdgcn_sched_barrier(0);
        __builtin_amdgcn_s_barrier();
    }

    // ---- row sums: 16 threads per row are one 16-lane group ----
    float v = rs;
    v += __shfl_xor(v, 1, 64); v += __shfl_xor(v, 2, 64);
    v += __shfl_xor(v, 4, 64); v += __shfl_xor(v, 8, 64);
    if ((lane & 15) == 0) wsumS[(wid << 2) + (lane >> 4)] = v;
    __syncthreads();
    if (t < 16) invS[t] = 1.0f / wsumS[t];
    __syncthreads();

    // ---- normalized G1 tile (C layout validated in R6) ----
    #pragma unroll
    for (int i = 0; i < 4; ++i) {
        const int ro = (kg << 2) + i;
        g1[ro * G1S + (wid << 4) + r] = acc[i] * invS[ro];
    }
    __syncthreads();

    // ---- Dense(64) + tanh (R6 verbatim) ----
    const int row0 = wid << 2;
    const float* g1r = g1 + row0 * G1S;
    float o0 = bdv[lane], o1 = o0, o2 = o0, o3 = o0;
    #pragma unroll 4
    for (int f = 0; f < Ff; ++f) {
        float wdv = Wd[f * Uu + lane];
        o0 += g1r[f]           * wdv;
        o1 += g1r[G1S + f]     * wdv;
        o2 += g1r[2 * G1S + f] * wdv;
        o3 += g1r[3 * G1S + f] * wdv;
    }
    float oo[4] = {o0, o1, o2, o3};
    #pragma unroll
    for (int i = 0; i < 4; ++i) {
        float x  = fminf(fmaxf(oo[i], -15.f), 15.f);
        float ex = __expf(2.f * x);
        out[((size_t)b * Nn + n0 + row0 + i) * Uu + lane] = (ex - 1.f) / (ex + 1.f);
    }
}

extern "C" void kernel_launch(void* const* d_in, const int* in_sizes, int n_in,
                              void* d_out, int out_size, void* d_ws, size_t ws_size,
                              hipStream_t stream) {
    const float* X   = (const float*)d_in[0];
    const float* Dyn = (const float*)d_in[1];
    const float* Wf  = (const float*)d_in[2];
    const float* Geo = (const float*)d_in[3];
    const float* KLm = (const float*)d_in[4];
    const float* Wd  = (const float*)d_in[5];
    const float* bdv = (const float*)d_in[6];
    float* out = (float*)d_out;

    _Float16* Xt = (_Float16*)d_ws;   // 2 MB scratch (ws verified >= 2MB)
    transposeX<<<dim3(8, Nn / 64), dim3(256), 0, stream>>>(X, Xt);
    fused_gcn<<<dim3(8 * (Nn / 16)), dim3(NT), 0, stream>>>(
        Xt, Dyn, Wf, Geo, KLm, Wd, bdv, out);
}